// Round 10
// baseline (21122.653 us; speedup 1.0000x reference)
//
#include <hip/hip_runtime.h>

// MyRNN: x_{t+1} = x_t + 0.1*(-x_t + (Jij*M) @ sigmoid(x_t) + II[:,t]), x_0 = 0
// out[2048][4096] row-major; col 0 = 0, cols 1..4095 = x_1..x_4095.
//
// Round 10 = round 9 with the fetch leg overlapped into the detect leg:
//  - board fetch uses relaxed agent ATOMIC loads (coherence-point served,
//    proven by rounds 1/5/8/9 straggler+watcher loops) -> NO acquire fence,
//    one fewer __syncthreads, no buffer_inv per step.
//  - the 2 pair-loads are issued SPECULATIVELY at exchange entry, before the
//    watcher spin: early producers' pairs verify instantly, the spin hides
//    the load latency; only late pairs re-load (one RT, data already at L3).
//  - publish (sigmoid -> tagged pairs -> slot hint) fires immediately after
//    the x-update; out-banking and the 64-step out-flush moved after it.
// Everything else identical to round 9 (64 blocks x 1024 thr, J 64 VGPR/lane,
// tagged self-validating pairs, fence-free spins, deferred coalesced out,
// II register prefetch). 0xAA ws-poison = invalid tags/slots, no memset.

#define NN   2048
#define LT   4096
#define NBLK 64
#define TPB  1024
#define SPIN_CAP 100000

typedef unsigned long long ull_t;

__device__ __forceinline__ ull_t pack_sv(unsigned tag, float v)
{
    return ((ull_t)tag << 32) | (ull_t)__float_as_uint(v);
}

__global__ __launch_bounds__(TPB, 1)
void rnn_persistent(const float* __restrict__ II,
                    const float* __restrict__ Jij,
                    const float* __restrict__ Mm,
                    float* __restrict__ out,
                    ull_t* __restrict__ board,   // [2][NN] {tag,val} pairs
                    int* __restrict__ slots)     // [NBLK] @ 32-int (128B) stride
{
    // 64 chunks x 32 floats, pad 33 -> 2-way bank alias (free). Single buffer:
    // the post-fetch barrier of step t separates compute reads from t+1 writes.
    __shared__ float s_lds[64 * 33];

    const int tid  = threadIdx.x;
    const int lane = tid & 63;
    const int wv   = tid >> 6;                 // 0..15
    const int bid  = blockIdx.x;
    const int r0   = bid * 32 + 2 * wv;        // 32 rows per block
    const int r1   = r0 + 1;
    const int colb = lane * 32;

    // ---- one-time: J_eff = Jij * M into registers (2 rows x 32 cols/lane) ----
    float jr0[32], jr1[32];
    {
        const float4* a0 = reinterpret_cast<const float4*>(Jij + (size_t)r0 * NN + colb);
        const float4* m0 = reinterpret_cast<const float4*>(Mm  + (size_t)r0 * NN + colb);
        const float4* a1 = reinterpret_cast<const float4*>(Jij + (size_t)r1 * NN + colb);
        const float4* m1 = reinterpret_cast<const float4*>(Mm  + (size_t)r1 * NN + colb);
#pragma unroll
        for (int k = 0; k < 8; ++k) {
            float4 a = a0[k], m = m0[k];
            jr0[4*k+0] = a.x * m.x; jr0[4*k+1] = a.y * m.y;
            jr0[4*k+2] = a.z * m.z; jr0[4*k+3] = a.w * m.w;
            float4 b = a1[k], n = m1[k];
            jr1[4*k+0] = b.x * n.x; jr1[4*k+1] = b.y * n.y;
            jr1[4*k+2] = b.z * n.z; jr1[4*k+3] = b.w * n.w;
        }
    }

    float x0 = 0.f, x1 = 0.f;   // state, replicated across lanes (bit-identical)
    float vx0 = 0.f, vx1 = 0.f; // deferred-out bank: lane j holds col (cb+j); col 0 stays 0
    float ii0 = 0.f, ii1 = 0.f; // II prefetch: lane l holds II[r, tbase+l]

    for (int t = 0; t < LT - 1; ++t) {
        // refill II prefetch every 64 steps (coalesced; consumed via shfl below)
        if ((t & 63) == 0) {
            ii0 = II[(size_t)r0 * LT + t + lane];
            ii1 = II[(size_t)r1 * LT + t + lane];
        }

        if (t == 0) {
            // s_0 = sigmoid(0) = 0.5 everywhere: no exchange needed.
            const int idx = tid * 2;
            float* p = &s_lds[(idx >> 5) * 33 + (idx & 31)];
            p[0] = 0.5f; p[1] = 0.5f;
            __syncthreads();
        } else {
            const ull_t* pp = board + (size_t)(t & 1) * NN + tid * 2;
            // ---- speculative fetch: issue own 2 pair-loads NOW (atomic =>
            // coherence-point served, no fence needed); the watcher spin below
            // hides their latency, and early producers verify instantly.
            ull_t a = __hip_atomic_load(pp + 0, __ATOMIC_RELAXED, __HIP_MEMORY_SCOPE_AGENT);
            ull_t b = __hip_atomic_load(pp + 1, __ATOMIC_RELAXED, __HIP_MEMORY_SCOPE_AGENT);
            // ---- detect (hint): 64 watchers, one private slot line each ----
            if (tid < NBLK) {
                int iters = 0;
                while (__hip_atomic_load(slots + tid * 32, __ATOMIC_RELAXED,
                                         __HIP_MEMORY_SCOPE_AGENT) < t) {
                    __builtin_amdgcn_s_sleep(1);
                    if (++iters > SPIN_CAP) break;   // anti-hang insurance
                }
            }
            __syncthreads();
            // ---- verify tags; late pairs re-load (data at L3 by now) ----
            const unsigned tg = (unsigned)t;
            int iters = 0;
            while ((unsigned)(a >> 32) != tg || (unsigned)(b >> 32) != tg) {
                a = __hip_atomic_load(pp + 0, __ATOMIC_RELAXED, __HIP_MEMORY_SCOPE_AGENT);
                b = __hip_atomic_load(pp + 1, __ATOMIC_RELAXED, __HIP_MEMORY_SCOPE_AGENT);
                if (++iters > SPIN_CAP) break;       // anti-hang insurance
                __builtin_amdgcn_s_sleep(1);
            }
            const int idx = tid * 2;
            float* p = &s_lds[(idx >> 5) * 33 + (idx & 31)];
            p[0] = __uint_as_float((unsigned)a);
            p[1] = __uint_as_float((unsigned)b);
            __syncthreads();
        }

        // ---- dot: 2 rows x 32 cols/lane, butterfly (all lanes get full sums) ----
        float acc0 = 0.f, acc1 = 0.f;
        const float* sl = &s_lds[lane * 33];
#pragma unroll
        for (int j = 0; j < 32; ++j) {
            float sv = sl[j];
            acc0 = fmaf(jr0[j], sv, acc0);
            acc1 = fmaf(jr1[j], sv, acc1);
        }
#pragma unroll
        for (int m = 32; m > 0; m >>= 1) {
            acc0 += __shfl_xor(acc0, m, 64);
            acc1 += __shfl_xor(acc1, m, 64);
        }

        const float It0 = __shfl(ii0, t & 63, 64);
        const float It1 = __shfl(ii1, t & 63, 64);
        x0 = x0 + 0.1f * (-x0 + acc0 + It0);
        x1 = x1 + 0.1f * (-x1 + acc1 + It1);

        const int tp1 = t + 1;

        // ---- publish FIRST (critical path): sigmoid -> tagged pairs -> hint ----
        if (tp1 <= LT - 2) {
            if (lane == 0) {
                const float s0 = 1.f / (1.f + __expf(-x0));
                const float s1 = 1.f / (1.f + __expf(-x1));
                ull_t* wr = board + (size_t)(tp1 & 1) * NN;
                __hip_atomic_store(wr + r0, pack_sv((unsigned)tp1, s0),
                                   __ATOMIC_RELAXED, __HIP_MEMORY_SCOPE_AGENT);
                __hip_atomic_store(wr + r1, pack_sv((unsigned)tp1, s1),
                                   __ATOMIC_RELAXED, __HIP_MEMORY_SCOPE_AGENT);
            }
            if (tid == 0) {
                __hip_atomic_store(slots + bid * 32, tp1,
                                   __ATOMIC_RELAXED, __HIP_MEMORY_SCOPE_AGENT);
            }
        }

        // ---- out-banking off the critical path ----
        if (lane == (tp1 & 63)) { vx0 = x0; vx1 = x1; }
        if ((tp1 & 63) == 63) {
            const int cb = tp1 & ~63;
            out[(size_t)r0 * LT + cb + lane] = vx0;
            out[(size_t)r1 * LT + cb + lane] = vx1;
        }
    }
}

extern "C" void kernel_launch(void* const* d_in, const int* in_sizes, int n_in,
                              void* d_out, int out_size, void* d_ws, size_t ws_size,
                              hipStream_t stream)
{
    const float* II  = (const float*)d_in[0];
    const float* Jij = (const float*)d_in[1];
    const float* Mm  = (const float*)d_in[2];
    float* out = (float*)d_out;

    unsigned char* ws = (unsigned char*)d_ws;
    ull_t* board = (ull_t*)(ws + 0);       // 2*2048*8B = 32 KB tagged pairs
    int*   slots = (int*)(ws + 32768);     // 64 slots * 128B = 8 KB

    // ws re-poisoned to 0xAA before every replay -> slots read 0xAAAAAAAA
    // (negative => "not arrived") and board tags never match; no memset needed.
    rnn_persistent<<<NBLK, TPB, 0, stream>>>(II, Jij, Mm, out, board, slots);
}